// Round 7
// baseline (1188.721 us; speedup 1.0000x reference)
//
#include <hip/hip_runtime.h>
#include <stdint.h>
#include <stddef.h>

// S=8192, D=1024 causal attention + QKV proj.
// fused cast->bf16, QKV MFMA GEMM (async LDS staging; writes Q/K/V in blocked
// MFMA-fragment layouts), flash attention (Br=64, Bc=256, 8 waves, pair-balanced
// grid + key-parity split-2, 2-pass P buffer to fit 150KB LDS), merge.

#define SEQ   8192
#define DIM   1024

typedef __bf16 bf16x8 __attribute__((ext_vector_type(8)));
typedef float  f32x4  __attribute__((ext_vector_type(4)));

#define MFMA16(a, b, c) __builtin_amdgcn_mfma_f32_16x16x32_bf16((a), (b), (c), 0, 0, 0)

__device__ __forceinline__ uint16_t f2bf(float f) {
  uint32_t u = __builtin_bit_cast(uint32_t, f);
  return (uint16_t)((u + 0x7fffu + ((u >> 16) & 1u)) >> 16);
}
__device__ __forceinline__ float bf2f(uint16_t h) {
  uint32_t u = ((uint32_t)h) << 16;
  return __builtin_bit_cast(float, u);
}

typedef const __attribute__((address_space(1))) uint32_t* gas_t;
typedef __attribute__((address_space(3))) uint32_t* las_t;
__device__ __forceinline__ void async16(const void* g, void* l) {
  __builtin_amdgcn_global_load_lds((gas_t)g, (las_t)l, 16, 0, 0);
}

// ------------------------------------------------------- fused cast kernel
__global__ __launch_bounds__(256) void cast_all(const float* __restrict__ x,
                                                const float* __restrict__ wq,
                                                const float* __restrict__ wk,
                                                const float* __restrict__ wv,
                                                uint16_t* __restrict__ xb,
                                                uint16_t* __restrict__ wcat) {
  int b = blockIdx.x;
  const float* src;
  uint16_t* dst;
  int i;
  if (b < 8192) {
    src = x; dst = xb; i = (b * 256 + threadIdx.x) * 4;
  } else {
    int wb = b - 8192;
    int sel = wb >> 10;
    src = sel == 0 ? wq : (sel == 1 ? wk : wv);
    dst = wcat + sel * 1048576;
    i = ((wb & 1023) * 256 + threadIdx.x) * 4;
  }
  float4 v = *(const float4*)(src + i);
  ushort4 o;
  o.x = f2bf(v.x); o.y = f2bf(v.y); o.z = f2bf(v.z); o.w = f2bf(v.w);
  *(ushort4*)(dst + i) = o;
}

// ------------------------------------------------------------- QKV GEMM
// async LDS staging (XOR-swizzled), 128x128 tile, BK=64.
// Epilogue scatters Q,K into blocked A/B-frag layout, V into blocked B-frag.
__global__ __launch_bounds__(256) void qkv_gemm(const uint16_t* __restrict__ A,
                                                const uint16_t* __restrict__ B,
                                                uint16_t* __restrict__ Qblk,
                                                uint16_t* __restrict__ Kblk,
                                                uint16_t* __restrict__ Vblk) {
  __shared__ __align__(16) uint16_t As[128 * 64];
  __shared__ __align__(16) uint16_t Bs[128 * 64];
  const int t    = threadIdx.x;
  const int w    = t >> 6;
  const int lane = t & 63;
  const int lm   = lane & 15;
  const int qd   = lane >> 4;
  const int wrow = (w >> 1) * 64;
  const int wcol = (w & 1) * 64;
  const int rowbase = blockIdx.y * 128;
  const int colbase = blockIdx.x * 128;

  const int lrow = lane >> 3;
  const int lgrp = (lane & 7) ^ (lrow & 7);

  f32x4 acc[4][4] = {};

  for (int kb = 0; kb < DIM; kb += 64) {
    __syncthreads();
#pragma unroll
    for (int rep = 0; rep < 4; ++rep) {
      int r0 = rep * 32 + w * 8;
      async16(A + (size_t)(rowbase + r0 + lrow) * DIM + kb + lgrp * 8, As + r0 * 64);
      async16(B + (size_t)(colbase + r0 + lrow) * DIM + kb + lgrp * 8, Bs + r0 * 64);
    }
    __syncthreads();
#pragma unroll
    for (int kc = 0; kc < 2; ++kc) {
      bf16x8 af[4], bfr[4];
#pragma unroll
      for (int mt = 0; mt < 4; ++mt) {
        int r = wrow + mt * 16 + lm;
        af[mt] = *(const bf16x8*)(As + r * 64 + (((kc * 4 + qd) ^ (lm & 7)) * 8));
      }
#pragma unroll
      for (int nt = 0; nt < 4; ++nt) {
        int r = wcol + nt * 16 + lm;
        bfr[nt] = *(const bf16x8*)(Bs + r * 64 + (((kc * 4 + qd) ^ (lm & 7)) * 8));
      }
#pragma unroll
      for (int mt = 0; mt < 4; ++mt)
#pragma unroll
        for (int nt = 0; nt < 4; ++nt)
          acc[mt][nt] = MFMA16(af[mt], bfr[nt], acc[mt][nt]);
    }
  }

#pragma unroll
  for (int mt = 0; mt < 4; ++mt)
#pragma unroll
    for (int nt = 0; nt < 4; ++nt)
#pragma unroll
      for (int r = 0; r < 4; ++r) {
        int m = rowbase + wrow + mt * 16 + qd * 4 + r;
        int n = colbase + wcol + nt * 16 + lm;
        uint16_t v = f2bf(acc[mt][nt][r]);
        int nn = n & 1023;
        if (n < 2048) {
          size_t off = (((size_t)(m >> 4) * 32 + (nn >> 5)) * 64 +
                        ((nn >> 3) & 3) * 16 + (m & 15)) * 8 + (nn & 7);
          if (n < 1024) Qblk[off] = v; else Kblk[off] = v;
        } else {
          size_t off = (((size_t)(nn >> 4) * 256 + (m >> 5)) * 64 +
                        ((m >> 3) & 3) * 16 + (nn & 15)) * 8 + (m & 7);
          Vblk[off] = v;
        }
      }
}

// ------------------------------------------------------------ flash attention
// Br=64 rows, Bc=256 keys/iter, 8 waves (512 thr), 2 waves/SIMD.
// grid=256: p=b>>1 in [0,128): halves tt=p then 127-p; parity par=b&1,
// jg=par,par+2,... Phase A: wave w owns S cols [32w,+32) (4 m-tiles x 2
// n-tiles); Q from 128KB LDS (blocked), K direct global (blocked). Softmax in
// registers, pv packed in regs. Phase C: two 128-key passes through a 16KB Pb
// half-buffer; wave w owns d-slice [128w,+128); V direct global (blocked).
__global__ __launch_bounds__(512, 2) void attn_kernel(const uint16_t* __restrict__ Qblk,
                                                      const uint16_t* __restrict__ Kblk,
                                                      const uint16_t* __restrict__ Vblk,
                                                      uint16_t* __restrict__ P0,
                                                      uint16_t* __restrict__ P1,
                                                      float* __restrict__ Mm,
                                                      float* __restrict__ Ll) {
  __shared__ __align__(16) uint16_t Qs[65536];   // 128KB blocked Q tile (64 rows)
  __shared__ __align__(16) uint16_t Pb[8192];    // 16KB P half (A-frag blocked)
  __shared__ float stats[64][8];
  __shared__ float mrow[64];

  const int t    = threadIdx.x;
  const int w    = t >> 6;
  const int lane = t & 63;
  const int lm   = lane & 15;
  const int qd   = lane >> 4;
  const int wk   = w & 3;    // kc chunk within pass for Pb writes
  const int wp   = w >> 2;   // which pass this wave's P-cols belong to
  const int par  = blockIdx.x & 1;
  const int p    = blockIdx.x >> 1;
  const float c1 = 0.045084220027780106f;  // log2(e)/sqrt(1024)

#pragma unroll 1
  for (int half = 0; half < 2; ++half) {
    const int tt   = half ? 127 - p : p;
    const int row0 = tt * 64;
    const int jn   = (tt >> 2) + 1;   // # of 256-key tiles

    __syncthreads();  // previous half done with Qs/Pb
    // stage Q tile: contiguous 128KB from Qblk rows [tt*64, +64)
#pragma unroll
    for (int i = 0; i < 16; ++i)
      async16(Qblk + (size_t)tt * 65536 + i * 4096 + w * 512 + lane * 8,
              Qs + i * 4096 + w * 512);
    __syncthreads();  // drain DMA

    float m_run[4][4], l_run[4][4];
#pragma unroll
    for (int mt = 0; mt < 4; ++mt)
#pragma unroll
      for (int r = 0; r < 4; ++r) { m_run[mt][r] = -1e30f; l_run[mt][r] = 0.0f; }
    f32x4 o_acc[4][8] = {};

#pragma unroll 1
    for (int jg = par; jg < jn; jg += 2) {
      const uint16_t* kbp = Kblk + ((size_t)(jg * 16 + w * 2) * 32) * 512 + lane * 8;
      const uint16_t* qsp = Qs + lane * 8;

      // ---- Phase A: sacc[4][2] = Q K^T (64 rows x 32 cols this wave) -----
      f32x4 sacc[4][2] = {};
#pragma unroll 4
      for (int kb = 0; kb < 32; ++kb) {
        bf16x8 k0 = *(const bf16x8*)(kbp + (size_t)kb * 512);
        bf16x8 k1 = *(const bf16x8*)(kbp + (size_t)(16384 + kb * 512));
#pragma unroll
        for (int mt = 0; mt < 4; ++mt) {
          bf16x8 q = *(const bf16x8*)(qsp + (mt * 32 + kb) * 512);
          sacc[mt][0] = MFMA16(q, k0, sacc[mt][0]);
          sacc[mt][1] = MFMA16(q, k1, sacc[mt][1]);
        }
      }

      // ---- causal mask (diagonal tile only) ------------------------------
      if (jg == jn - 1) {
#pragma unroll
        for (int mt = 0; mt < 4; ++mt)
#pragma unroll
          for (int nt = 0; nt < 2; ++nt)
#pragma unroll
            for (int r = 0; r < 4; ++r) {
              int col = jg * 256 + w * 32 + nt * 16 + lm;
              int row = row0 + mt * 16 + qd * 4 + r;
              if (col > row) sacc[mt][nt][r] = -1e30f;
            }
      }

      // ---- wave-local row max -> stats -----------------------------------
#pragma unroll
      for (int mt = 0; mt < 4; ++mt)
#pragma unroll
        for (int r = 0; r < 4; ++r) {
          float v = fmaxf(sacc[mt][0][r], sacc[mt][1][r]);
          v = fmaxf(v, __shfl_xor(v, 1));
          v = fmaxf(v, __shfl_xor(v, 2));
          v = fmaxf(v, __shfl_xor(v, 4));
          v = fmaxf(v, __shfl_xor(v, 8));
          if (lm == 0) stats[mt * 16 + qd * 4 + r][w] = v;
        }
      __syncthreads();  // (1) stats ready; gates Pb reuse from prev iter

      // ---- softmax in registers; pv packed -------------------------------
      float alpha[4][4];
      uint32_t pvp[4][2][2];  // [mt][nt][r-pair] two bf16 packed
#pragma unroll
      for (int mt = 0; mt < 4; ++mt) {
        float psum[4];
#pragma unroll
        for (int r = 0; r < 4; ++r) {
          int rl = mt * 16 + qd * 4 + r;
          float4 g0 = *(const float4*)&stats[rl][0];
          float4 g1 = *(const float4*)&stats[rl][4];
          float gm = fmaxf(fmaxf(fmaxf(g0.x, g0.y), fmaxf(g0.z, g0.w)),
                           fmaxf(fmaxf(g1.x, g1.y), fmaxf(g1.z, g1.w)));
          float mn = fmaxf(m_run[mt][r], gm);
          alpha[mt][r] = exp2f((m_run[mt][r] - mn) * c1);
          m_run[mt][r] = mn;
          psum[r] = 0.0f;
        }
#pragma unroll
        for (int nt = 0; nt < 2; ++nt)
#pragma unroll
          for (int rp = 0; rp < 2; ++rp) {
            float pv0 = exp2f((sacc[mt][nt][rp * 2 + 0] - m_run[mt][rp * 2 + 0]) * c1);
            float pv1 = exp2f((sacc[mt][nt][rp * 2 + 1] - m_run[mt][rp * 2 + 1]) * c1);
            psum[rp * 2 + 0] += pv0;
            psum[rp * 2 + 1] += pv1;
            pvp[mt][nt][rp] = (uint32_t)f2bf(pv0) | ((uint32_t)f2bf(pv1) << 16);
          }
#pragma unroll
        for (int r = 0; r < 4; ++r) {
          float s2 = psum[r];
          s2 += __shfl_xor(s2, 1);
          s2 += __shfl_xor(s2, 2);
          s2 += __shfl_xor(s2, 4);
          s2 += __shfl_xor(s2, 8);
          l_run[mt][r] = l_run[mt][r] * alpha[mt][r] + s2;
        }
      }
      // waves 0..3 write pass-0 P (keys [jg*256, +128))
      if (wp == 0) {
#pragma unroll
        for (int mt = 0; mt < 4; ++mt)
#pragma unroll
          for (int nt = 0; nt < 2; ++nt)
#pragma unroll
            for (int rp = 0; rp < 2; ++rp) {
              int base = ((mt * 4 + wk) * 64 + (nt * 2 + (lm >> 3)) * 16 + qd * 4 + rp * 2) * 8 +
                         (lm & 7);
              Pb[base]     = (uint16_t)(pvp[mt][nt][rp] & 0xffff);
              Pb[base + 8] = (uint16_t)(pvp[mt][nt][rp] >> 16);
            }
      }
      __syncthreads();  // (2) Pb pass-0 ready

      // ---- rescale O -----------------------------------------------------
#pragma unroll
      for (int mt = 0; mt < 4; ++mt)
#pragma unroll
        for (int dt = 0; dt < 8; ++dt)
#pragma unroll
          for (int r = 0; r < 4; ++r)
            o_acc[mt][dt][r] *= alpha[mt][r];

      // ---- C pass 0: keys [jg*256, +128) ---------------------------------
      const uint16_t* vbp = Vblk + (((size_t)(w * 8) * 256 + jg * 8) * 64) * 8 + lane * 8;
#pragma unroll
      for (int kc = 0; kc < 4; ++kc) {
        bf16x8 pf[4];
#pragma unroll
        for (int mt = 0; mt < 4; ++mt)
          pf[mt] = *(const bf16x8*)(Pb + ((mt * 4 + kc) * 64 + lane) * 8);
#pragma unroll
        for (int dt = 0; dt < 8; ++dt) {
          bf16x8 vf = *(const bf16x8*)(vbp + ((size_t)dt * 256 + kc) * 512);
#pragma unroll
          for (int mt = 0; mt < 4; ++mt)
            o_acc[mt][dt] = MFMA16(pf[mt], vf, o_acc[mt][dt]);
        }
      }
      __syncthreads();  // (3) Pb pass-0 consumed
      if (wp == 1) {
#pragma unroll
        for (int mt = 0; mt < 4; ++mt)
#pragma unroll
          for (int nt = 0; nt < 2; ++nt)
#pragma unroll
            for (int rp = 0; rp < 2; ++rp) {
              int base = ((mt * 4 + wk) * 64 + (nt * 2 + (lm >> 3)) * 16 + qd * 4 + rp * 2) * 8 +
                         (lm & 7);
              Pb[base]     = (uint16_t)(pvp[mt][nt][rp] & 0xffff);
              Pb[base + 8] = (uint16_t)(pvp[mt][nt][rp] >> 16);
            }
      }
      __syncthreads();  // (4) Pb pass-1 ready

      // ---- C pass 1: keys [jg*256+128, +128) -----------------------------
#pragma unroll
      for (int kc = 0; kc < 4; ++kc) {
        bf16x8 pf[4];
#pragma unroll
        for (int mt = 0; mt < 4; ++mt)
          pf[mt] = *(const bf16x8*)(Pb + ((mt * 4 + kc) * 64 + lane) * 8);
#pragma unroll
        for (int dt = 0; dt < 8; ++dt) {
          bf16x8 vf = *(const bf16x8*)(vbp + ((size_t)dt * 256 + 4 + kc) * 512);
#pragma unroll
          for (int mt = 0; mt < 4; ++mt)
            o_acc[mt][dt] = MFMA16(pf[mt], vf, o_acc[mt][dt]);
        }
      }
    }

    // ---- epilogue: stats (reused as lsum) + unnormalized partial O -------
    __syncthreads();
    if (lm == 0) {
#pragma unroll
      for (int mt = 0; mt < 4; ++mt)
#pragma unroll
        for (int r = 0; r < 4; ++r) {
          int rl = mt * 16 + qd * 4 + r;
          stats[rl][w] = l_run[mt][r];
          if (w == 0) mrow[rl] = m_run[mt][r];
        }
    }
    __syncthreads();
    if (t < 64) {
      float4 a0 = *(const float4*)&stats[t][0];
      float4 a1 = *(const float4*)&stats[t][4];
      Mm[par * SEQ + row0 + t] = mrow[t];
      Ll[par * SEQ + row0 + t] = (a0.x + a0.y + a0.z + a0.w) + (a1.x + a1.y + a1.z + a1.w);
    }
    uint16_t* Pp = par ? P1 : P0;
#pragma unroll
    for (int mt = 0; mt < 4; ++mt)
#pragma unroll
      for (int dt = 0; dt < 8; ++dt)
#pragma unroll
        for (int r = 0; r < 4; ++r) {
          int row = row0 + mt * 16 + qd * 4 + r;
          int d   = w * 128 + dt * 16 + lm;
          Pp[(size_t)row * DIM + d] = f2bf(o_acc[mt][dt][r]);
        }
  }
}

// ------------------------------------------------------------ merge partials
__global__ __launch_bounds__(256) void merge_kernel(const uint16_t* __restrict__ P0,
                                                    const uint16_t* __restrict__ P1,
                                                    const float* __restrict__ Mm,
                                                    const float* __restrict__ Ll,
                                                    float* __restrict__ out) {
  const int row = blockIdx.x;
  const int d0  = threadIdx.x * 4;
  const float c1 = 0.045084220027780106f;
  float m0 = Mm[row], m1 = Mm[SEQ + row];
  float l0 = Ll[row], l1 = Ll[SEQ + row];
  float m  = fmaxf(m0, m1);
  float a0 = exp2f((m0 - m) * c1);
  float a1 = exp2f((m1 - m) * c1);
  float inv = 1.0f / (a0 * l0 + a1 * l1);
  ushort4 p0 = *(const ushort4*)(P0 + (size_t)row * DIM + d0);
  ushort4 p1 = *(const ushort4*)(P1 + (size_t)row * DIM + d0);
  float4 o;
  o.x = (a0 * bf2f(p0.x) + a1 * bf2f(p1.x)) * inv;
  o.y = (a0 * bf2f(p0.y) + a1 * bf2f(p1.y)) * inv;
  o.z = (a0 * bf2f(p0.z) + a1 * bf2f(p1.z)) * inv;
  o.w = (a0 * bf2f(p0.w) + a1 * bf2f(p1.w)) * inv;
  *(float4*)(out + (size_t)row * DIM + d0) = o;
}

// ---------------------------------------------------------------- launch
extern "C" void kernel_launch(void* const* d_in, const int* in_sizes, int n_in,
                              void* d_out, int out_size, void* d_ws, size_t ws_size,
                              hipStream_t stream) {
  (void)in_sizes; (void)n_in; (void)out_size; (void)ws_size;
  const float* x  = (const float*)d_in[0];
  const float* wq = (const float*)d_in[1];
  const float* wk = (const float*)d_in[2];
  const float* wv = (const float*)d_in[3];
  float* out = (float*)d_out;

  char* ws = (char*)d_ws;
  uint16_t* Qblk = (uint16_t*)(ws);                  // 16MB blocked
  uint16_t* Kblk = (uint16_t*)(ws + 16777216);       // 16MB blocked
  uint16_t* Vblk = (uint16_t*)(ws + 33554432);       // 16MB blocked
  uint16_t* P0   = (uint16_t*)(ws + 50331648);       // 16MB partial 0
  uint16_t* xb   = (uint16_t*)(ws + 67108864);       // 16MB
  uint16_t* P1   = (uint16_t*)(ws + 67108864);       // aliases xb (dead after GEMM)
  uint16_t* wcat = (uint16_t*)(ws + 83886080);       // 6MB
  float*    Mm   = (float*)(ws + 83886080);          // aliases wcat (dead after GEMM)
  float*    Ll   = (float*)(ws + 83886080 + 65536);

  cast_all<<<11264, 256, 0, stream>>>(x, wq, wk, wv, xb, wcat);
  qkv_gemm<<<dim3(24, 64), 256, 0, stream>>>(xb, wcat, Qblk, Kblk, Vblk);
  attn_kernel<<<256, 512, 0, stream>>>(Qblk, Kblk, Vblk, P0, P1, Mm, Ll);
  merge_kernel<<<SEQ, 256, 0, stream>>>(P0, P1, Mm, Ll, out);
}